// Round 2
// baseline (456.952 us; speedup 1.0000x reference)
//
#include <hip/hip_runtime.h>

// Classifier: out[40000][10] = (mean_J relu(x @ Wloc^T)) @ W^T
// x: [1200000][64] f32, Wloc: [128][64] f32, W: [10][128] f32.
//
// v3: same contiguous-slab MFMA mapping as v2 (M-dim = rows-within-segment,
// 15 valid rows + 1 zero pad per 16-row tile), but tuned for occupancy:
//  - one-tile-ahead pipeline (16 prefetch VGPRs instead of 64) -> fits
//    __launch_bounds__(256,4) = 16 waves/CU (was 8).
//  - 40 segs/block -> grid = 1000 blocks, all co-resident at 4 blocks/CU,
//    no partial-machine tail round (v2's 625-block grid had a 113-block tail).
//  - LDS 25.9 KB/block (x4 = 103.7 KB/CU <= 160).

typedef __bf16 bf16x8 __attribute__((ext_vector_type(8)));
typedef float f32x4 __attribute__((ext_vector_type(4)));

#define JJ 30
#define DIN 64
#define DENC 128
#define NCLS 10
#define SEG_PER_BLOCK 40   // 4 waves * 10 segments
#define SEG_PER_WAVE 10
#define FEATP 130          // padded leading dim for s_feats

union FragU { unsigned u[4]; bf16x8 v; };

// pack two f32 -> one dword of two bf16 (round-to-nearest via +0x8000, then
// v_perm_b32 grabs the high halves). hi lands in bits 31:16, lo in 15:0.
__device__ __forceinline__ unsigned pk_rn(float hi, float lo) {
  unsigned uh = __builtin_bit_cast(unsigned, hi) + 0x8000u;
  unsigned ul = __builtin_bit_cast(unsigned, lo) + 0x8000u;
  return __builtin_amdgcn_perm(uh, ul, 0x07060302u);
}

struct Tile { float4 a, b, c, d; };

// p already carries the per-lane offset (lrow*DIN + quad*8). Lanes with
// lrow==15 are the pad row: they load nothing and stay zero.
__device__ __forceinline__ void load_tile(const float* __restrict__ p, bool act, Tile& t) {
  if (act) {
    t.a = *(const float4*)p;
    t.b = *(const float4*)(p + 4);
    t.c = *(const float4*)(p + 32);
    t.d = *(const float4*)(p + 36);
  } else {
    t.a = make_float4(0.f, 0.f, 0.f, 0.f);
    t.b = make_float4(0.f, 0.f, 0.f, 0.f);
    t.c = make_float4(0.f, 0.f, 0.f, 0.f);
    t.d = make_float4(0.f, 0.f, 0.f, 0.f);
  }
}

// convert one 16-row tile to bf16 A-frags, run 16 MFMAs, relu+pool into part.
// C/D layout: row (tile row) = quad*4+rg, col = nt*16 + (lane&15).
__device__ __forceinline__ void accum_tile(const Tile& t, const FragU (&wb)[8][2],
                                           float (&part)[8]) {
  FragU a0, a1;
  a0.u[0] = pk_rn(t.a.y, t.a.x); a0.u[1] = pk_rn(t.a.w, t.a.z);
  a0.u[2] = pk_rn(t.b.y, t.b.x); a0.u[3] = pk_rn(t.b.w, t.b.z);
  a1.u[0] = pk_rn(t.c.y, t.c.x); a1.u[1] = pk_rn(t.c.w, t.c.z);
  a1.u[2] = pk_rn(t.d.y, t.d.x); a1.u[3] = pk_rn(t.d.w, t.d.z);
#pragma unroll
  for (int nt = 0; nt < 8; ++nt) {
    f32x4 z = {0.f, 0.f, 0.f, 0.f};
    f32x4 acc = __builtin_amdgcn_mfma_f32_16x16x32_bf16(a0.v, wb[nt][0].v, z, 0, 0, 0);
    acc = __builtin_amdgcn_mfma_f32_16x16x32_bf16(a1.v, wb[nt][1].v, acc, 0, 0, 0);
#pragma unroll
    for (int rg = 0; rg < 4; ++rg) part[nt] += fmaxf(acc[rg], 0.f);
  }
}

__global__ __launch_bounds__(256, 4)
void classifier_kernel(const float* __restrict__ x,
                       const float* __restrict__ wloc,
                       const float* __restrict__ w,
                       float* __restrict__ out) {
  __shared__ float s_feats[SEG_PER_BLOCK * FEATP]; // 20,800 B
  __shared__ float s_w[NCLS * DENC];               //  5,120 B

  const int tid  = threadIdx.x;
  const int wid  = tid >> 6;
  const int lane = tid & 63;
  const int quad = lane >> 4;
  const int lrow = lane & 15;

  // stage W into LDS (read after the single __syncthreads below)
  for (int i = tid; i < NCLS * DENC; i += 256) s_w[i] = w[i];

  // B fragments: whole Wloc in registers (verified layout):
  // lane -> (n = lane&15, k = quad*8 + j); element =
  // Wloc[e = nt*16 + lrow][d = ks*32 + quad*8 + j], j consecutive.
  FragU wb[8][2];
#pragma unroll
  for (int nt = 0; nt < 8; ++nt) {
#pragma unroll
    for (int ks = 0; ks < 2; ++ks) {
      const float* p = wloc + (nt * 16 + lrow) * DIN + ks * 32 + quad * 8;
      float4 f0 = *(const float4*)p;
      float4 f1 = *(const float4*)(p + 4);
      wb[nt][ks].u[0] = pk_rn(f0.y, f0.x);
      wb[nt][ks].u[1] = pk_rn(f0.w, f0.z);
      wb[nt][ks].u[2] = pk_rn(f1.y, f1.x);
      wb[nt][ks].u[3] = pk_rn(f1.w, f1.z);
    }
  }

  const int seg0 = blockIdx.x * SEG_PER_BLOCK + wid * SEG_PER_WAVE;
  const size_t srow = (size_t)seg0 * JJ;            // wave's first x-row
  const bool act = (lrow < 15);                     // lrow==15 is pad row
  // per-lane base: row lrow of a tile, k-offset quad*8
  const float* xl = x + (size_t)lrow * DIN + quad * 8;

  const float inv = 1.0f / 30.0f;

  // half-tile software pipeline: tiles stream as t = 0..2*SEG_PER_WAVE-1,
  // tile t covers rows [seg*30 + (t&1)*15, +15) of segment seg = t>>1.
  Tile cur, nxt;
  load_tile(xl + srow * DIN, act, cur);

  float part[8];
  const int NT = SEG_PER_WAVE * 2;
#pragma unroll 2
  for (int t = 0; t < NT; ++t) {
    if (t + 1 < NT) {
      size_t nrow = srow + (size_t)((t + 1) >> 1) * JJ + (size_t)(((t + 1) & 1) * 15);
      load_tile(xl + nrow * DIN, act, nxt);
    }

    if ((t & 1) == 0) {
#pragma unroll
      for (int nt = 0; nt < 8; ++nt) part[nt] = 0.f;
    }

    accum_tile(cur, wb, part);

    if (t & 1) {
      // cross-quad reduce: lanes {lrow, lrow+16, lrow+32, lrow+48} hold the
      // 4 row-group partials of this segment; butterfly over bits 4,5.
      const int segl = wid * SEG_PER_WAVE + (t >> 1);
#pragma unroll
      for (int nt = 0; nt < 8; ++nt) {
        float v = part[nt];
        v += __shfl_xor(v, 16);
        v += __shfl_xor(v, 32);
        if (quad == 0)
          s_feats[segl * FEATP + nt * 16 + lrow] = v * inv;
      }
    }

    cur = nxt;
  }

  __syncthreads();

  // final tiny matmul: out[seg][c] = dot(feats[seg], W[c]) ; 400 outputs/block
  for (int i = tid; i < SEG_PER_BLOCK * NCLS; i += 256) {
    int sg = i / NCLS;
    int c  = i - sg * NCLS;
    const float* fr = s_feats + sg * FEATP;
    const float* wr = s_w + c * DENC;
    float acc = 0.f;
#pragma unroll 8
    for (int e = 0; e < DENC; ++e) acc += fr[e] * wr[e];
    out[(size_t)(blockIdx.x * SEG_PER_BLOCK + sg) * NCLS + c] = acc;
  }
}

extern "C" void kernel_launch(void* const* d_in, const int* in_sizes, int n_in,
                              void* d_out, int out_size, void* d_ws, size_t ws_size,
                              hipStream_t stream) {
  const float* x    = (const float*)d_in[0];
  const float* wloc = (const float*)d_in[1];
  const float* w    = (const float*)d_in[2];
  float* out = (float*)d_out;
  // 40000 segments / 40 per block = 1000 blocks, all co-resident at 4/CU
  classifier_kernel<<<dim3(1000), dim3(256), 0, stream>>>(x, wloc, w, out);
}

// Round 3
// 428.310 us; speedup vs baseline: 1.0669x; 1.0669x over previous
//
#include <hip/hip_runtime.h>

// Classifier: out[40000][10] = (mean_J relu(x @ Wloc^T)) @ W^T
// x: [1200000][64] f32, Wloc: [128][64] f32, W: [10][128] f32.
//
// v4 = v2's proven datapath (contiguous-slab MFMA mapping, M-dim =
// rows-within-segment, 15 valid rows + 1 zero pad per 16-row tile,
// full-segment two-tile-ahead prefetch, launch_bounds(256,2)) with ONE
// structural change: balanced persistent grid.
//   512 blocks = 2048 waves = exactly 2 blocks/CU, all co-resident.
//   Wave gw owns segments [gw*19 + min(gw,1088), +19 or 20)  (40000 = 2048*19 + 1088).
//   v2's 625-block grid ran as 2 rounds on 512 slots (round 2: 113 blocks,
//   399 idle slots). This removes that tail entirely.
// Epilogue is wave-local (waves have unequal n; no __syncthreads after loop).

typedef __bf16 bf16x8 __attribute__((ext_vector_type(8)));
typedef float f32x4 __attribute__((ext_vector_type(4)));

#define JJ 30
#define DIN 64
#define DENC 128
#define NCLS 10
#define MAXSEG_W 20        // max segments per wave
#define FEATP 130          // padded leading dim for s_feats

union FragU { unsigned u[4]; bf16x8 v; };

// pack two f32 -> one dword of two bf16 (round-to-nearest via +0x8000, then
// v_perm_b32 grabs the high halves). hi lands in bits 31:16, lo in 15:0.
__device__ __forceinline__ unsigned pk_rn(float hi, float lo) {
  unsigned uh = __builtin_bit_cast(unsigned, hi) + 0x8000u;
  unsigned ul = __builtin_bit_cast(unsigned, lo) + 0x8000u;
  return __builtin_amdgcn_perm(uh, ul, 0x07060302u);
}

struct Tile { float4 a, b, c, d; };

// p already carries the per-lane offset (lrow*DIN + quad*8). Lanes with
// lrow==15 are the pad row: they load nothing and stay zero.
__device__ __forceinline__ void load_tile(const float* __restrict__ p, bool act, Tile& t) {
  if (act) {
    t.a = *(const float4*)p;
    t.b = *(const float4*)(p + 4);
    t.c = *(const float4*)(p + 32);
    t.d = *(const float4*)(p + 36);
  } else {
    t.a = make_float4(0.f, 0.f, 0.f, 0.f);
    t.b = make_float4(0.f, 0.f, 0.f, 0.f);
    t.c = make_float4(0.f, 0.f, 0.f, 0.f);
    t.d = make_float4(0.f, 0.f, 0.f, 0.f);
  }
}

// convert one 16-row tile to bf16 A-frags, run 16 MFMAs, relu+pool into part.
// C/D layout: row (tile row) = quad*4+rg, col = nt*16 + (lane&15).
__device__ __forceinline__ void accum_tile(const Tile& t, const FragU (&wb)[8][2],
                                           float (&part)[8]) {
  FragU a0, a1;
  a0.u[0] = pk_rn(t.a.y, t.a.x); a0.u[1] = pk_rn(t.a.w, t.a.z);
  a0.u[2] = pk_rn(t.b.y, t.b.x); a0.u[3] = pk_rn(t.b.w, t.b.z);
  a1.u[0] = pk_rn(t.c.y, t.c.x); a1.u[1] = pk_rn(t.c.w, t.c.z);
  a1.u[2] = pk_rn(t.d.y, t.d.x); a1.u[3] = pk_rn(t.d.w, t.d.z);
#pragma unroll
  for (int nt = 0; nt < 8; ++nt) {
    f32x4 z = {0.f, 0.f, 0.f, 0.f};
    f32x4 acc = __builtin_amdgcn_mfma_f32_16x16x32_bf16(a0.v, wb[nt][0].v, z, 0, 0, 0);
    acc = __builtin_amdgcn_mfma_f32_16x16x32_bf16(a1.v, wb[nt][1].v, acc, 0, 0, 0);
#pragma unroll
    for (int rg = 0; rg < 4; ++rg) part[nt] += fmaxf(acc[rg], 0.f);
  }
}

__global__ __launch_bounds__(256, 2)
void classifier_kernel(const float* __restrict__ x,
                       const float* __restrict__ wloc,
                       const float* __restrict__ w,
                       float* __restrict__ out) {
  __shared__ float s_feats[4 * MAXSEG_W * FEATP]; // 41,600 B
  __shared__ float s_w[NCLS * DENC];              //  5,120 B

  const int tid  = threadIdx.x;
  const int wid  = tid >> 6;
  const int lane = tid & 63;
  const int quad = lane >> 4;
  const int lrow = lane & 15;

  // stage W into LDS; single barrier, then everything is wave-local
  for (int i = tid; i < NCLS * DENC; i += 256) s_w[i] = w[i];
  __syncthreads();

  // B fragments: whole Wloc in registers (verified layout):
  // lane -> (n = lane&15, k = quad*8 + j); element =
  // Wloc[e = nt*16 + lrow][d = ks*32 + quad*8 + j], j consecutive.
  FragU wb[8][2];
#pragma unroll
  for (int nt = 0; nt < 8; ++nt) {
#pragma unroll
    for (int ks = 0; ks < 2; ++ks) {
      const float* p = wloc + (nt * 16 + lrow) * DIN + ks * 32 + quad * 8;
      float4 f0 = *(const float4*)p;
      float4 f1 = *(const float4*)(p + 4);
      wb[nt][ks].u[0] = pk_rn(f0.y, f0.x);
      wb[nt][ks].u[1] = pk_rn(f0.w, f0.z);
      wb[nt][ks].u[2] = pk_rn(f1.y, f1.x);
      wb[nt][ks].u[3] = pk_rn(f1.w, f1.z);
    }
  }

  // balanced persistent assignment: 40000 = 2048*19 + 1088
  const int gw = blockIdx.x * 4 + wid;
  const int n  = 19 + (gw < 1088 ? 1 : 0);
  const int s0 = gw * 19 + (gw < 1088 ? gw : 1088);

  const size_t srow = (size_t)s0 * JJ;              // wave's first x-row
  const bool act = (lrow < 15);                     // lrow==15 is pad row
  // per-lane base: row lrow of a tile, k-offset quad*8
  const float* xl = x + (size_t)lrow * DIN + quad * 8;

  const float inv = 1.0f / 30.0f;

  Tile tA, tB, nA, nB;
  load_tile(xl + srow * DIN, act, tA);              // seg 0, rows 0..14
  load_tile(xl + (srow + 15) * DIN, act, tB);       // seg 0, rows 15..29

  for (int i = 0; i < n; ++i) {
    // prefetch next segment's two tiles (distance-1-segment, ~7.7 KB/wave)
    if (i + 1 < n) {
      size_t nrow = srow + (size_t)(i + 1) * JJ;
      load_tile(xl + nrow * DIN, act, nA);
      load_tile(xl + (nrow + 15) * DIN, act, nB);
    }

    float part[8] = {0.f, 0.f, 0.f, 0.f, 0.f, 0.f, 0.f, 0.f};
    accum_tile(tA, wb, part);
    accum_tile(tB, wb, part);

    // cross-quad reduce: lanes {lrow, lrow+16, lrow+32, lrow+48} hold the
    // 4 row-group partials of segment i; butterfly over bits 4,5.
#pragma unroll
    for (int nt = 0; nt < 8; ++nt) {
      float v = part[nt];
      v += __shfl_xor(v, 16);
      v += __shfl_xor(v, 32);
      if (quad == 0)
        s_feats[(wid * MAXSEG_W + i) * FEATP + nt * 16 + lrow] = v * inv;
    }

    tA = nA; tB = nB;
  }

  // wave-local epilogue: same-wave LDS RAW needs an explicit drain (cross-lane
  // visibility within the wave is ordered by lgkmcnt, not program order).
  asm volatile("s_waitcnt lgkmcnt(0)" ::: "memory");

  // out[seg][c] = dot(feats[seg], W[c]) ; n*10 outputs per wave
  for (int j = lane; j < n * NCLS; j += 64) {
    int sg = j / NCLS;
    int c  = j - sg * NCLS;
    const float* fr = s_feats + (wid * MAXSEG_W + sg) * FEATP;
    const float* wr = s_w + c * DENC;
    float acc = 0.f;
#pragma unroll 8
    for (int e = 0; e < DENC; ++e) acc += fr[e] * wr[e];
    out[(size_t)(s0 + sg) * NCLS + c] = acc;
  }
}

extern "C" void kernel_launch(void* const* d_in, const int* in_sizes, int n_in,
                              void* d_out, int out_size, void* d_ws, size_t ws_size,
                              hipStream_t stream) {
  const float* x    = (const float*)d_in[0];
  const float* wloc = (const float*)d_in[1];
  const float* w    = (const float*)d_in[2];
  float* out = (float*)d_out;
  // 512 blocks = 2048 waves, exactly 2 blocks/CU, all co-resident, balanced
  classifier_kernel<<<dim3(512), dim3(256), 0, stream>>>(x, wloc, w, out);
}

// Round 6
// 421.100 us; speedup vs baseline: 1.0851x; 1.0171x over previous
//
#include <hip/hip_runtime.h>

// Classifier: out[40000][10] = (mean_J relu(x @ Wloc^T)) @ W^T
// x: [1200000][64] f32, Wloc: [128][64] f32, W: [10][128] f32.
//
// v5 = v4 (balanced persistent grid: 512 blocks = 2048 waves, all co-resident
// at 2 blocks/CU; wave gw owns segments [gw*19+min(gw,1088), +19|20);
// contiguous-slab MFMA mapping, 15 valid rows + 1 zero pad per 16-row tile,
// distance-1-segment prefetch) with an epilogue fix:
//  - LDS strides padded to 132 floats (528 B: rows 16B-aligned, bank stride 4
//    -> worst 2-way conflict, free). Old s_w stride 128 put all 10 class rows
//    in the SAME bank per element -> ~10-way serialization on every read.
//  - epilogue dot vectorized as float4 ds_read_b128 (32 iters instead of 128).
// (Third submission; prior two attempts failed with infra-side container
// errors — same error mode previously seen with a known-good kernel.)

typedef __bf16 bf16x8 __attribute__((ext_vector_type(8)));
typedef float f32x4 __attribute__((ext_vector_type(4)));

#define JJ 30
#define DIN 64
#define DENC 128
#define NCLS 10
#define MAXSEG_W 20        // max segments per wave
#define FEATP 132          // padded stride: 528 B, 16B-aligned, bank stride 4
#define WP 132             // s_w padded stride

union FragU { unsigned u[4]; bf16x8 v; };

// pack two f32 -> one dword of two bf16 (round-to-nearest via +0x8000, then
// v_perm_b32 grabs the high halves). hi lands in bits 31:16, lo in 15:0.
__device__ __forceinline__ unsigned pk_rn(float hi, float lo) {
  unsigned uh = __builtin_bit_cast(unsigned, hi) + 0x8000u;
  unsigned ul = __builtin_bit_cast(unsigned, lo) + 0x8000u;
  return __builtin_amdgcn_perm(uh, ul, 0x07060302u);
}

struct Tile { float4 a, b, c, d; };

// p already carries the per-lane offset (lrow*DIN + quad*8). Lanes with
// lrow==15 are the pad row: they load nothing and stay zero.
__device__ __forceinline__ void load_tile(const float* __restrict__ p, bool act, Tile& t) {
  if (act) {
    t.a = *(const float4*)p;
    t.b = *(const float4*)(p + 4);
    t.c = *(const float4*)(p + 32);
    t.d = *(const float4*)(p + 36);
  } else {
    t.a = make_float4(0.f, 0.f, 0.f, 0.f);
    t.b = make_float4(0.f, 0.f, 0.f, 0.f);
    t.c = make_float4(0.f, 0.f, 0.f, 0.f);
    t.d = make_float4(0.f, 0.f, 0.f, 0.f);
  }
}

// convert one 16-row tile to bf16 A-frags, run 16 MFMAs, relu+pool into part.
// C/D layout: row (tile row) = quad*4+rg, col = nt*16 + (lane&15).
__device__ __forceinline__ void accum_tile(const Tile& t, const FragU (&wb)[8][2],
                                           float (&part)[8]) {
  FragU a0, a1;
  a0.u[0] = pk_rn(t.a.y, t.a.x); a0.u[1] = pk_rn(t.a.w, t.a.z);
  a0.u[2] = pk_rn(t.b.y, t.b.x); a0.u[3] = pk_rn(t.b.w, t.b.z);
  a1.u[0] = pk_rn(t.c.y, t.c.x); a1.u[1] = pk_rn(t.c.w, t.c.z);
  a1.u[2] = pk_rn(t.d.y, t.d.x); a1.u[3] = pk_rn(t.d.w, t.d.z);
#pragma unroll
  for (int nt = 0; nt < 8; ++nt) {
    f32x4 z = {0.f, 0.f, 0.f, 0.f};
    f32x4 acc = __builtin_amdgcn_mfma_f32_16x16x32_bf16(a0.v, wb[nt][0].v, z, 0, 0, 0);
    acc = __builtin_amdgcn_mfma_f32_16x16x32_bf16(a1.v, wb[nt][1].v, acc, 0, 0, 0);
#pragma unroll
    for (int rg = 0; rg < 4; ++rg) part[nt] += fmaxf(acc[rg], 0.f);
  }
}

__global__ __launch_bounds__(256, 2)
void classifier_kernel(const float* __restrict__ x,
                       const float* __restrict__ wloc,
                       const float* __restrict__ w,
                       float* __restrict__ out) {
  __shared__ float s_feats[4 * MAXSEG_W * FEATP]; // 42,240 B
  __shared__ float s_w[NCLS * WP];                //  5,280 B

  const int tid  = threadIdx.x;
  const int wid  = tid >> 6;
  const int lane = tid & 63;
  const int quad = lane >> 4;
  const int lrow = lane & 15;

  // stage W into LDS (padded stride); single barrier, then all wave-local
  for (int i = tid; i < NCLS * DENC; i += 256)
    s_w[(i >> 7) * WP + (i & 127)] = w[i];
  __syncthreads();

  // B fragments: whole Wloc in registers (verified layout):
  // lane -> (n = lane&15, k = quad*8 + j); element =
  // Wloc[e = nt*16 + lrow][d = ks*32 + quad*8 + j], j consecutive.
  FragU wb[8][2];
#pragma unroll
  for (int nt = 0; nt < 8; ++nt) {
#pragma unroll
    for (int ks = 0; ks < 2; ++ks) {
      const float* p = wloc + (nt * 16 + lrow) * DIN + ks * 32 + quad * 8;
      float4 f0 = *(const float4*)p;
      float4 f1 = *(const float4*)(p + 4);
      wb[nt][ks].u[0] = pk_rn(f0.y, f0.x);
      wb[nt][ks].u[1] = pk_rn(f0.w, f0.z);
      wb[nt][ks].u[2] = pk_rn(f1.y, f1.x);
      wb[nt][ks].u[3] = pk_rn(f1.w, f1.z);
    }
  }

  // balanced persistent assignment: 40000 = 2048*19 + 1088
  const int gw = blockIdx.x * 4 + wid;
  const int n  = 19 + (gw < 1088 ? 1 : 0);
  const int s0 = gw * 19 + (gw < 1088 ? gw : 1088);

  const size_t srow = (size_t)s0 * JJ;              // wave's first x-row
  const bool act = (lrow < 15);                     // lrow==15 is pad row
  // per-lane base: row lrow of a tile, k-offset quad*8
  const float* xl = x + (size_t)lrow * DIN + quad * 8;

  const float inv = 1.0f / 30.0f;

  Tile tA, tB, nA, nB;
  load_tile(xl + srow * DIN, act, tA);              // seg 0, rows 0..14
  load_tile(xl + (srow + 15) * DIN, act, tB);       // seg 0, rows 15..29

  for (int i = 0; i < n; ++i) {
    // prefetch next segment's two tiles (distance-1-segment, ~7.7 KB/wave)
    if (i + 1 < n) {
      size_t nrow = srow + (size_t)(i + 1) * JJ;
      load_tile(xl + nrow * DIN, act, nA);
      load_tile(xl + (nrow + 15) * DIN, act, nB);
    }

    float part[8] = {0.f, 0.f, 0.f, 0.f, 0.f, 0.f, 0.f, 0.f};
    accum_tile(tA, wb, part);
    accum_tile(tB, wb, part);

    // cross-quad reduce: lanes {lrow, lrow+16, lrow+32, lrow+48} hold the
    // 4 row-group partials of segment i; butterfly over bits 4,5.
#pragma unroll
    for (int nt = 0; nt < 8; ++nt) {
      float v = part[nt];
      v += __shfl_xor(v, 16);
      v += __shfl_xor(v, 32);
      if (quad == 0)
        s_feats[(wid * MAXSEG_W + i) * FEATP + nt * 16 + lrow] = v * inv;
    }

    tA = nA; tB = nB;
  }

  // wave-local epilogue: same-wave LDS RAW needs an explicit drain (cross-lane
  // visibility within the wave is ordered by lgkmcnt, not program order).
  asm volatile("s_waitcnt lgkmcnt(0)" ::: "memory");

  // out[seg][c] = dot(feats[seg], W[c]) ; n*10 outputs per wave.
  // float4 LDS reads: rows 16B-aligned (stride 132), banks spread by 4 ->
  // worst 2-way conflict (free).
  for (int j = lane; j < n * NCLS; j += 64) {
    int sg = j / NCLS;
    int c  = j - sg * NCLS;
    const float4* fr = (const float4*)(s_feats + (wid * MAXSEG_W + sg) * FEATP);
    const float4* wr = (const float4*)(s_w + c * WP);
    float4 a4 = make_float4(0.f, 0.f, 0.f, 0.f);
#pragma unroll 8
    for (int e = 0; e < DENC / 4; ++e) {
      float4 f = fr[e], g = wr[e];
      a4.x += f.x * g.x; a4.y += f.y * g.y;
      a4.z += f.z * g.z; a4.w += f.w * g.w;
    }
    out[(size_t)(s0 + sg) * NCLS + c] = (a4.x + a4.y) + (a4.z + a4.w);
  }
}

extern "C" void kernel_launch(void* const* d_in, const int* in_sizes, int n_in,
                              void* d_out, int out_size, void* d_ws, size_t ws_size,
                              hipStream_t stream) {
  const float* x    = (const float*)d_in[0];
  const float* wloc = (const float*)d_in[1];
  const float* w    = (const float*)d_in[2];
  float* out = (float*)d_out;
  // 512 blocks = 2048 waves, exactly 2 blocks/CU, all co-resident, balanced
  classifier_kernel<<<dim3(512), dim3(256), 0, stream>>>(x, wloc, w, out);
}